// Round 1
// baseline (1202.088 us; speedup 1.0000x reference)
//
#include <hip/hip_runtime.h>
#include <hip/hip_bf16.h>

#define N_NODES 20000
#define N_EDGES 320000

typedef __attribute__((ext_vector_type(8))) short short8;
typedef __attribute__((ext_vector_type(4))) float f32x4;

static __device__ __forceinline__ ushort f2bf(float f) {
  union { float f; uint u; } v; v.f = f;
  uint u = v.u;
  uint r = (u + 0x7FFFu + ((u >> 16) & 1u)) >> 16;
  return (ushort)r;
}
static __device__ __forceinline__ float bf2f(ushort s) {
  union { uint u; float f; } v; v.u = ((uint)s) << 16; return v.f;
}

// Stage a 64x32 tile into LDS as bf16 [64][32]. 256 threads: 4 threads/row,
// 8 consecutive elements each. Rows >= mrem are zero-filled.
static __device__ __forceinline__ void stage_f32(ushort* lds, const float* __restrict__ src,
                                                 int ld, int mrem) {
  int t = threadIdx.x;
  int row = t >> 2;
  int col = (t & 3) << 3;
  union { ushort s[8]; uint4 v; } tmp;
  if (row < mrem) {
    const float* p = src + (size_t)row * ld + col;
    float4 v0 = *(const float4*)p;
    float4 v1 = *(const float4*)(p + 4);
    tmp.s[0]=f2bf(v0.x); tmp.s[1]=f2bf(v0.y); tmp.s[2]=f2bf(v0.z); tmp.s[3]=f2bf(v0.w);
    tmp.s[4]=f2bf(v1.x); tmp.s[5]=f2bf(v1.y); tmp.s[6]=f2bf(v1.z); tmp.s[7]=f2bf(v1.w);
  } else {
    tmp.v = make_uint4(0,0,0,0);
  }
  *(uint4*)&lds[row*32 + col] = tmp.v;
}

static __device__ __forceinline__ void stage_bf16(ushort* lds, const ushort* __restrict__ src,
                                                  int ld, int mrem) {
  int t = threadIdx.x;
  int row = t >> 2;
  int col = (t & 3) << 3;
  uint4 v = make_uint4(0,0,0,0);
  if (row < mrem) v = *(const uint4*)(src + (size_t)row * ld + col);
  *(uint4*)&lds[row*32 + col] = v;
}

// ---------------- K1: xr = relu([x|h] @ Wfc^T + bfc), store bf16 ----------------
__global__ __launch_bounds__(256) void k_fc(
    const float* __restrict__ x, const float* __restrict__ h,
    const float* __restrict__ Wfc, const float* __restrict__ bfc,
    ushort* __restrict__ xr) {
  __shared__ ushort sA[64*32], sB[64*32];
  int row0 = blockIdx.x * 64;
  int col0 = blockIdx.y * 64;
  int mrem = N_NODES - row0; if (mrem > 64) mrem = 64;
  int w = threadIdx.x >> 6, l = threadIdx.x & 63;
  int wr = (w >> 1) * 32, wc = (w & 1) * 32;
  f32x4 acc[2][2] = {};
  for (int kb = 0; kb < 16; ++kb) {
    int k0 = kb * 32;
    const float* asrc = (k0 < 256) ? (x + (size_t)row0*256 + k0)
                                   : (h + (size_t)row0*256 + (k0-256));
    stage_f32(sA, asrc, 256, mrem);
    stage_f32(sB, Wfc + (size_t)col0*512 + k0, 512, 64);
    __syncthreads();
    short8 a[2], b[2];
    #pragma unroll
    for (int i=0;i<2;i++) a[i] = *(short8*)&sA[(wr + i*16 + (l&15))*32 + (l>>4)*8];
    #pragma unroll
    for (int i=0;i<2;i++) b[i] = *(short8*)&sB[(wc + i*16 + (l&15))*32 + (l>>4)*8];
    #pragma unroll
    for (int mi=0;mi<2;mi++)
      #pragma unroll
      for (int ni=0;ni<2;ni++)
        acc[mi][ni] = __builtin_amdgcn_mfma_f32_16x16x32_bf16(a[mi], b[ni], acc[mi][ni], 0,0,0);
    __syncthreads();
  }
  #pragma unroll
  for (int mi=0;mi<2;mi++)
    #pragma unroll
    for (int ni=0;ni<2;ni++)
      #pragma unroll
      for (int q=0;q<4;q++) {
        int r = row0 + wr + mi*16 + (l>>4)*4 + q;
        int c = col0 + wc + ni*16 + (l&15);
        if (r < N_NODES) {
          float v = acc[mi][ni][q] + bfc[c];
          v = v > 0.f ? v : 0.f;
          xr[(size_t)r*256 + c] = f2bf(v);
        }
      }
}

// ---------------- W_conv transpose -> bf16 ----------------
__global__ void k_transpose_wc(const float* __restrict__ Wc, ushort* __restrict__ WcT) {
  int j = blockIdx.x;
  int k = threadIdx.x;
  WcT[j*256 + k] = f2bf(Wc[k*256 + j]);
}

// ---------------- K2: m = xr @ WcT^T (NT), bf16 in/out ----------------
__global__ __launch_bounds__(256) void k_conv(
    const ushort* __restrict__ xr, const ushort* __restrict__ WcT,
    ushort* __restrict__ m) {
  __shared__ ushort sA[64*32], sB[64*32];
  int row0 = blockIdx.x * 64;
  int col0 = blockIdx.y * 64;
  int mrem = N_NODES - row0; if (mrem > 64) mrem = 64;
  int w = threadIdx.x >> 6, l = threadIdx.x & 63;
  int wr = (w >> 1) * 32, wc = (w & 1) * 32;
  f32x4 acc[2][2] = {};
  for (int kb = 0; kb < 8; ++kb) {
    int k0 = kb * 32;
    stage_bf16(sA, xr + (size_t)row0*256 + k0, 256, mrem);
    stage_bf16(sB, WcT + (size_t)col0*256 + k0, 256, 64);
    __syncthreads();
    short8 a[2], b[2];
    #pragma unroll
    for (int i=0;i<2;i++) a[i] = *(short8*)&sA[(wr + i*16 + (l&15))*32 + (l>>4)*8];
    #pragma unroll
    for (int i=0;i<2;i++) b[i] = *(short8*)&sB[(wc + i*16 + (l&15))*32 + (l>>4)*8];
    #pragma unroll
    for (int mi=0;mi<2;mi++)
      #pragma unroll
      for (int ni=0;ni<2;ni++)
        acc[mi][ni] = __builtin_amdgcn_mfma_f32_16x16x32_bf16(a[mi], b[ni], acc[mi][ni], 0,0,0);
    __syncthreads();
  }
  #pragma unroll
  for (int mi=0;mi<2;mi++)
    #pragma unroll
    for (int ni=0;ni<2;ni++)
      #pragma unroll
      for (int q=0;q<4;q++) {
        int r = row0 + wr + mi*16 + (l>>4)*4 + q;
        int c = col0 + wc + ni*16 + (l&15);
        if (r < N_NODES) m[(size_t)r*256 + c] = f2bf(acc[mi][ni][q]);
      }
}

// ---------------- K3: scatter-add agg[dst] += m[src] ----------------
__global__ __launch_bounds__(256) void k_scatter(
    const int* __restrict__ eg, const ushort* __restrict__ m,
    float* __restrict__ agg) {
  int idx = blockIdx.x * 256 + threadIdx.x;
  int e = idx >> 6;
  if (e >= N_EDGES) return;
  int lane = idx & 63;
  int src = eg[e];
  int dst = eg[N_EDGES + e];
  ushort4 mv = *(const ushort4*)(m + (size_t)src*256 + lane*4);
  float* ap = agg + (size_t)dst*256 + lane*4;
  unsafeAtomicAdd(ap+0, bf2f(mv.x));
  unsafeAtomicAdd(ap+1, bf2f(mv.y));
  unsafeAtomicAdd(ap+2, bf2f(mv.z));
  unsafeAtomicAdd(ap+3, bf2f(mv.w));
}

// ---------------- K4: fused GRU (6 GEMM tiles + elementwise) ----------------
__global__ __launch_bounds__(256) void k_gru(
    const float* __restrict__ agg, const ushort* __restrict__ xr,
    const float* __restrict__ Wih, const float* __restrict__ Whh,
    const float* __restrict__ bih, const float* __restrict__ bhh,
    float* __restrict__ out) {
  __shared__ ushort sAa[64*32], sAx[64*32], sBi[3][64*32], sBh[3][64*32];
  int row0 = blockIdx.x * 64;
  int col0 = blockIdx.y * 64;
  int mrem = N_NODES - row0; if (mrem > 64) mrem = 64;
  int w = threadIdx.x >> 6, l = threadIdx.x & 63;
  int wr = (w >> 1) * 32, wc = (w & 1) * 32;
  f32x4 acc[6][2][2] = {};  // 0..2: i_r,i_z,i_n   3..5: h_r,h_z,h_n
  for (int kb = 0; kb < 8; ++kb) {
    int k0 = kb * 32;
    stage_f32 (sAa, agg + (size_t)row0*256 + k0, 256, mrem);
    stage_bf16(sAx, xr  + (size_t)row0*256 + k0, 256, mrem);
    #pragma unroll
    for (int c=0;c<3;c++) {
      stage_f32(sBi[c], Wih + ((size_t)(c*256 + col0))*256 + k0, 256, 64);
      stage_f32(sBh[c], Whh + ((size_t)(c*256 + col0))*256 + k0, 256, 64);
    }
    __syncthreads();
    short8 aa[2], ax[2], b;
    #pragma unroll
    for (int i=0;i<2;i++) {
      aa[i] = *(short8*)&sAa[(wr + i*16 + (l&15))*32 + (l>>4)*8];
      ax[i] = *(short8*)&sAx[(wr + i*16 + (l&15))*32 + (l>>4)*8];
    }
    #pragma unroll
    for (int c=0;c<3;c++) {
      #pragma unroll
      for (int ni=0;ni<2;ni++) {
        b = *(short8*)&sBi[c][(wc + ni*16 + (l&15))*32 + (l>>4)*8];
        #pragma unroll
        for (int mi=0;mi<2;mi++)
          acc[c][mi][ni] = __builtin_amdgcn_mfma_f32_16x16x32_bf16(aa[mi], b, acc[c][mi][ni],0,0,0);
        b = *(short8*)&sBh[c][(wc + ni*16 + (l&15))*32 + (l>>4)*8];
        #pragma unroll
        for (int mi=0;mi<2;mi++)
          acc[3+c][mi][ni] = __builtin_amdgcn_mfma_f32_16x16x32_bf16(ax[mi], b, acc[3+c][mi][ni],0,0,0);
      }
    }
    __syncthreads();
  }
  #pragma unroll
  for (int mi=0;mi<2;mi++)
    #pragma unroll
    for (int ni=0;ni<2;ni++)
      #pragma unroll
      for (int q=0;q<4;q++) {
        int r = row0 + wr + mi*16 + (l>>4)*4 + q;
        int c = col0 + wc + ni*16 + (l&15);
        if (r < N_NODES) {
          float ir  = acc[0][mi][ni][q] + bih[c];
          float iz  = acc[1][mi][ni][q] + bih[256+c];
          float inn = acc[2][mi][ni][q] + bih[512+c];
          float hr  = acc[3][mi][ni][q] + bhh[c];
          float hz  = acc[4][mi][ni][q] + bhh[256+c];
          float hn  = acc[5][mi][ni][q] + bhh[512+c];
          float rg = 1.f/(1.f + __expf(-(ir+hr)));
          float zg = 1.f/(1.f + __expf(-(iz+hz)));
          float ng = tanhf(inn + rg*hn);
          float xv = bf2f(xr[(size_t)r*256 + c]);
          out[(size_t)r*256 + c] = (1.f - zg)*ng + zg*xv;
        }
      }
}

extern "C" void kernel_launch(void* const* d_in, const int* in_sizes, int n_in,
                              void* d_out, int out_size, void* d_ws, size_t ws_size,
                              hipStream_t stream) {
  const float* h   = (const float*)d_in[0];
  const float* x   = (const float*)d_in[1];
  const float* Wfc = (const float*)d_in[3];
  const float* bfc = (const float*)d_in[4];
  const float* Wc  = (const float*)d_in[5];
  const float* Wih = (const float*)d_in[6];
  const float* Whh = (const float*)d_in[7];
  const float* bih = (const float*)d_in[8];
  const float* bhh = (const float*)d_in[9];
  const int*   eg  = (const int*)d_in[10];
  float* out = (float*)d_out;

  char* ws = (char*)d_ws;
  ushort* xr  = (ushort*)ws;                    // N*256*2 = 10,240,000 B
  ushort* m   = (ushort*)(ws + 10240000);       // 10,240,000 B
  float*  agg = (float*)(ws + 20480000);        // 20,480,000 B
  ushort* WcT = (ushort*)(ws + 40960000);       // 131,072 B

  hipMemsetAsync(agg, 0, (size_t)N_NODES*256*4, stream);
  k_transpose_wc<<<256, 256, 0, stream>>>(Wc, WcT);

  dim3 g1(313, 4);
  k_fc<<<g1, 256, 0, stream>>>(x, h, Wfc, bfc, xr);
  k_conv<<<g1, 256, 0, stream>>>(xr, WcT, m);

  int sc_blocks = (N_EDGES * 64 + 255) / 256;
  k_scatter<<<sc_blocks, 256, 0, stream>>>(eg, m, agg);

  k_gru<<<g1, 256, 0, stream>>>(agg, xr, Wih, Whh, bih, bhh, out);
}

// Round 2
// 247.368 us; speedup vs baseline: 4.8595x; 4.8595x over previous
//
#include <hip/hip_runtime.h>
#include <hip/hip_bf16.h>

#define N_NODES 20000
#define N_EDGES 320000

typedef __attribute__((ext_vector_type(8))) short short8;
typedef __attribute__((ext_vector_type(4))) float f32x4;

static __device__ __forceinline__ ushort f2bf(float f) {
  union { float f; uint u; } v; v.f = f;
  uint u = v.u;
  uint r = (u + 0x7FFFu + ((u >> 16) & 1u)) >> 16;
  return (ushort)r;
}
static __device__ __forceinline__ float bf2f(ushort s) {
  union { uint u; float f; } v; v.u = ((uint)s) << 16; return v.f;
}

// Stage a 64x32 tile into LDS as bf16 [64][32]. 256 threads: 4 threads/row,
// 8 consecutive elements each. Rows >= mrem are zero-filled.
static __device__ __forceinline__ void stage_f32(ushort* lds, const float* __restrict__ src,
                                                 int ld, int mrem) {
  int t = threadIdx.x;
  int row = t >> 2;
  int col = (t & 3) << 3;
  union { ushort s[8]; uint4 v; } tmp;
  if (row < mrem) {
    const float* p = src + (size_t)row * ld + col;
    float4 v0 = *(const float4*)p;
    float4 v1 = *(const float4*)(p + 4);
    tmp.s[0]=f2bf(v0.x); tmp.s[1]=f2bf(v0.y); tmp.s[2]=f2bf(v0.z); tmp.s[3]=f2bf(v0.w);
    tmp.s[4]=f2bf(v1.x); tmp.s[5]=f2bf(v1.y); tmp.s[6]=f2bf(v1.z); tmp.s[7]=f2bf(v1.w);
  } else {
    tmp.v = make_uint4(0,0,0,0);
  }
  *(uint4*)&lds[row*32 + col] = tmp.v;
}

static __device__ __forceinline__ void stage_bf16(ushort* lds, const ushort* __restrict__ src,
                                                  int ld, int mrem) {
  int t = threadIdx.x;
  int row = t >> 2;
  int col = (t & 3) << 3;
  uint4 v = make_uint4(0,0,0,0);
  if (row < mrem) v = *(const uint4*)(src + (size_t)row * ld + col);
  *(uint4*)&lds[row*32 + col] = v;
}

// ---------------- K1: xr = relu([x|h] @ Wfc^T + bfc), store bf16 ----------------
__global__ __launch_bounds__(256) void k_fc(
    const float* __restrict__ x, const float* __restrict__ h,
    const float* __restrict__ Wfc, const float* __restrict__ bfc,
    ushort* __restrict__ xr) {
  __shared__ ushort sA[64*32], sB[64*32];
  int row0 = blockIdx.x * 64;
  int col0 = blockIdx.y * 64;
  int mrem = N_NODES - row0; if (mrem > 64) mrem = 64;
  int w = threadIdx.x >> 6, l = threadIdx.x & 63;
  int wr = (w >> 1) * 32, wc = (w & 1) * 32;
  f32x4 acc[2][2] = {};
  for (int kb = 0; kb < 16; ++kb) {
    int k0 = kb * 32;
    const float* asrc = (k0 < 256) ? (x + (size_t)row0*256 + k0)
                                   : (h + (size_t)row0*256 + (k0-256));
    stage_f32(sA, asrc, 256, mrem);
    stage_f32(sB, Wfc + (size_t)col0*512 + k0, 512, 64);
    __syncthreads();
    short8 a[2], b[2];
    #pragma unroll
    for (int i=0;i<2;i++) a[i] = *(short8*)&sA[(wr + i*16 + (l&15))*32 + (l>>4)*8];
    #pragma unroll
    for (int i=0;i<2;i++) b[i] = *(short8*)&sB[(wc + i*16 + (l&15))*32 + (l>>4)*8];
    #pragma unroll
    for (int mi=0;mi<2;mi++)
      #pragma unroll
      for (int ni=0;ni<2;ni++)
        acc[mi][ni] = __builtin_amdgcn_mfma_f32_16x16x32_bf16(a[mi], b[ni], acc[mi][ni], 0,0,0);
    __syncthreads();
  }
  #pragma unroll
  for (int mi=0;mi<2;mi++)
    #pragma unroll
    for (int ni=0;ni<2;ni++)
      #pragma unroll
      for (int q=0;q<4;q++) {
        int r = row0 + wr + mi*16 + (l>>4)*4 + q;
        int c = col0 + wc + ni*16 + (l&15);
        if (r < N_NODES) {
          float v = acc[mi][ni][q] + bfc[c];
          v = v > 0.f ? v : 0.f;
          xr[(size_t)r*256 + c] = f2bf(v);
        }
      }
}

// ---------------- W_conv transpose -> bf16 ----------------
__global__ void k_transpose_wc(const float* __restrict__ Wc, ushort* __restrict__ WcT) {
  int j = blockIdx.x;
  int k = threadIdx.x;
  WcT[j*256 + k] = f2bf(Wc[k*256 + j]);
}

// ---------------- K2: m = xr @ WcT^T (NT), bf16 in/out ----------------
__global__ __launch_bounds__(256) void k_conv(
    const ushort* __restrict__ xr, const ushort* __restrict__ WcT,
    ushort* __restrict__ m) {
  __shared__ ushort sA[64*32], sB[64*32];
  int row0 = blockIdx.x * 64;
  int col0 = blockIdx.y * 64;
  int mrem = N_NODES - row0; if (mrem > 64) mrem = 64;
  int w = threadIdx.x >> 6, l = threadIdx.x & 63;
  int wr = (w >> 1) * 32, wc = (w & 1) * 32;
  f32x4 acc[2][2] = {};
  for (int kb = 0; kb < 8; ++kb) {
    int k0 = kb * 32;
    stage_bf16(sA, xr + (size_t)row0*256 + k0, 256, mrem);
    stage_bf16(sB, WcT + (size_t)col0*256 + k0, 256, 64);
    __syncthreads();
    short8 a[2], b[2];
    #pragma unroll
    for (int i=0;i<2;i++) a[i] = *(short8*)&sA[(wr + i*16 + (l&15))*32 + (l>>4)*8];
    #pragma unroll
    for (int i=0;i<2;i++) b[i] = *(short8*)&sB[(wc + i*16 + (l&15))*32 + (l>>4)*8];
    #pragma unroll
    for (int mi=0;mi<2;mi++)
      #pragma unroll
      for (int ni=0;ni<2;ni++)
        acc[mi][ni] = __builtin_amdgcn_mfma_f32_16x16x32_bf16(a[mi], b[ni], acc[mi][ni], 0,0,0);
    __syncthreads();
  }
  #pragma unroll
  for (int mi=0;mi<2;mi++)
    #pragma unroll
    for (int ni=0;ni<2;ni++)
      #pragma unroll
      for (int q=0;q<4;q++) {
        int r = row0 + wr + mi*16 + (l>>4)*4 + q;
        int c = col0 + wc + ni*16 + (l&15);
        if (r < N_NODES) m[(size_t)r*256 + c] = f2bf(acc[mi][ni][q]);
      }
}

// ---------------- CSR build: histogram / scan / bucket ----------------
__global__ __launch_bounds__(256) void k_hist(const int* __restrict__ eg, int* __restrict__ deg) {
  int e = blockIdx.x * 256 + threadIdx.x;
  if (e < N_EDGES) atomicAdd(&deg[eg[N_EDGES + e]], 1);
}

__global__ __launch_bounds__(256) void k_scan(const int* __restrict__ deg,
                                              int* __restrict__ offs, int* __restrict__ cursor) {
  __shared__ int part[256];
  int t = threadIdx.x;
  const int CH = 79;  // 256*79 = 20224 >= 20000
  int base = t * CH;
  int s = 0;
  for (int i = 0; i < CH; i++) { int idx = base + i; if (idx < N_NODES) s += deg[idx]; }
  part[t] = s; __syncthreads();
  for (int d = 1; d < 256; d <<= 1) {
    int v = (t >= d) ? part[t - d] : 0;
    __syncthreads();
    part[t] += v;
    __syncthreads();
  }
  int run = (t == 0) ? 0 : part[t - 1];
  for (int i = 0; i < CH; i++) {
    int idx = base + i;
    if (idx < N_NODES) { offs[idx] = run; cursor[idx] = run; run += deg[idx]; }
  }
}

__global__ __launch_bounds__(256) void k_bucket(const int* __restrict__ eg,
                                                int* __restrict__ cursor, int* __restrict__ srcs) {
  int e = blockIdx.x * 256 + threadIdx.x;
  if (e < N_EDGES) {
    int d = eg[N_EDGES + e];
    int slot = atomicAdd(&cursor[d], 1);
    srcs[slot] = eg[e];
  }
}

// ---------------- K3: gather-reduce agg[n] = sum_{src in bucket(n)} m[src] ----------------
__global__ __launch_bounds__(256) void k_agg(
    const int* __restrict__ offs, const int* __restrict__ deg, const int* __restrict__ srcs,
    const ushort* __restrict__ m, ushort* __restrict__ agg) {
  int node = blockIdx.x * 4 + (threadIdx.x >> 6);
  if (node >= N_NODES) return;
  int lane = threadIdx.x & 63;
  int off = offs[node];
  int n = deg[node];
  float a0 = 0.f, a1 = 0.f, a2 = 0.f, a3 = 0.f;
  int i = 0;
  for (; i + 1 < n; i += 2) {
    int s0 = srcs[off + i];
    int s1 = srcs[off + i + 1];
    ushort4 v0 = *(const ushort4*)(m + (size_t)s0 * 256 + lane * 4);
    ushort4 v1 = *(const ushort4*)(m + (size_t)s1 * 256 + lane * 4);
    a0 += bf2f(v0.x) + bf2f(v1.x);
    a1 += bf2f(v0.y) + bf2f(v1.y);
    a2 += bf2f(v0.z) + bf2f(v1.z);
    a3 += bf2f(v0.w) + bf2f(v1.w);
  }
  if (i < n) {
    int s0 = srcs[off + i];
    ushort4 v0 = *(const ushort4*)(m + (size_t)s0 * 256 + lane * 4);
    a0 += bf2f(v0.x); a1 += bf2f(v0.y); a2 += bf2f(v0.z); a3 += bf2f(v0.w);
  }
  ushort4 o;
  o.x = f2bf(a0); o.y = f2bf(a1); o.z = f2bf(a2); o.w = f2bf(a3);
  *(ushort4*)(agg + (size_t)node * 256 + lane * 4) = o;
}

// ---------------- K4: fused GRU (6 GEMM tiles + elementwise) ----------------
__global__ __launch_bounds__(256) void k_gru(
    const ushort* __restrict__ agg, const ushort* __restrict__ xr,
    const float* __restrict__ Wih, const float* __restrict__ Whh,
    const float* __restrict__ bih, const float* __restrict__ bhh,
    float* __restrict__ out) {
  __shared__ ushort sAa[64*32], sAx[64*32], sBi[3][64*32], sBh[3][64*32];
  int row0 = blockIdx.x * 64;
  int col0 = blockIdx.y * 64;
  int mrem = N_NODES - row0; if (mrem > 64) mrem = 64;
  int w = threadIdx.x >> 6, l = threadIdx.x & 63;
  int wr = (w >> 1) * 32, wc = (w & 1) * 32;
  f32x4 acc[6][2][2] = {};  // 0..2: i_r,i_z,i_n   3..5: h_r,h_z,h_n
  for (int kb = 0; kb < 8; ++kb) {
    int k0 = kb * 32;
    stage_bf16(sAa, agg + (size_t)row0*256 + k0, 256, mrem);
    stage_bf16(sAx, xr  + (size_t)row0*256 + k0, 256, mrem);
    #pragma unroll
    for (int c=0;c<3;c++) {
      stage_f32(sBi[c], Wih + ((size_t)(c*256 + col0))*256 + k0, 256, 64);
      stage_f32(sBh[c], Whh + ((size_t)(c*256 + col0))*256 + k0, 256, 64);
    }
    __syncthreads();
    short8 aa[2], ax[2], b;
    #pragma unroll
    for (int i=0;i<2;i++) {
      aa[i] = *(short8*)&sAa[(wr + i*16 + (l&15))*32 + (l>>4)*8];
      ax[i] = *(short8*)&sAx[(wr + i*16 + (l&15))*32 + (l>>4)*8];
    }
    #pragma unroll
    for (int c=0;c<3;c++) {
      #pragma unroll
      for (int ni=0;ni<2;ni++) {
        b = *(short8*)&sBi[c][(wc + ni*16 + (l&15))*32 + (l>>4)*8];
        #pragma unroll
        for (int mi=0;mi<2;mi++)
          acc[c][mi][ni] = __builtin_amdgcn_mfma_f32_16x16x32_bf16(aa[mi], b, acc[c][mi][ni],0,0,0);
        b = *(short8*)&sBh[c][(wc + ni*16 + (l&15))*32 + (l>>4)*8];
        #pragma unroll
        for (int mi=0;mi<2;mi++)
          acc[3+c][mi][ni] = __builtin_amdgcn_mfma_f32_16x16x32_bf16(ax[mi], b, acc[3+c][mi][ni],0,0,0);
      }
    }
    __syncthreads();
  }
  #pragma unroll
  for (int mi=0;mi<2;mi++)
    #pragma unroll
    for (int ni=0;ni<2;ni++)
      #pragma unroll
      for (int q=0;q<4;q++) {
        int r = row0 + wr + mi*16 + (l>>4)*4 + q;
        int c = col0 + wc + ni*16 + (l&15);
        if (r < N_NODES) {
          float ir  = acc[0][mi][ni][q] + bih[c];
          float iz  = acc[1][mi][ni][q] + bih[256+c];
          float inn = acc[2][mi][ni][q] + bih[512+c];
          float hr  = acc[3][mi][ni][q] + bhh[c];
          float hz  = acc[4][mi][ni][q] + bhh[256+c];
          float hn  = acc[5][mi][ni][q] + bhh[512+c];
          float rg = 1.f/(1.f + __expf(-(ir+hr)));
          float zg = 1.f/(1.f + __expf(-(iz+hz)));
          float ng = tanhf(inn + rg*hn);
          float xv = bf2f(xr[(size_t)r*256 + c]);
          out[(size_t)r*256 + c] = (1.f - zg)*ng + zg*xv;
        }
      }
}

extern "C" void kernel_launch(void* const* d_in, const int* in_sizes, int n_in,
                              void* d_out, int out_size, void* d_ws, size_t ws_size,
                              hipStream_t stream) {
  const float* h   = (const float*)d_in[0];
  const float* x   = (const float*)d_in[1];
  const float* Wfc = (const float*)d_in[3];
  const float* bfc = (const float*)d_in[4];
  const float* Wc  = (const float*)d_in[5];
  const float* Wih = (const float*)d_in[6];
  const float* Whh = (const float*)d_in[7];
  const float* bih = (const float*)d_in[8];
  const float* bhh = (const float*)d_in[9];
  const int*   eg  = (const int*)d_in[10];
  float* out = (float*)d_out;

  char* ws = (char*)d_ws;
  ushort* xr   = (ushort*)ws;                    // 10,240,000 B
  ushort* m    = (ushort*)(ws + 10240000);       // 10,240,000 B
  ushort* agg  = (ushort*)(ws + 20480000);       // 10,240,000 B
  ushort* WcT  = (ushort*)(ws + 30720000);       //    131,072 B
  int*    deg    = (int*)(ws + 30851072);        //     80,000 B
  int*    offs   = (int*)(ws + 30931072);        //     80,000 B
  int*    cursor = (int*)(ws + 31011072);        //     80,000 B
  int*    srcs   = (int*)(ws + 31091072);        //  1,280,000 B

  hipMemsetAsync(deg, 0, (size_t)N_NODES * 4, stream);
  k_transpose_wc<<<256, 256, 0, stream>>>(Wc, WcT);

  dim3 g1(313, 4);
  k_fc<<<g1, 256, 0, stream>>>(x, h, Wfc, bfc, xr);
  k_conv<<<g1, 256, 0, stream>>>(xr, WcT, m);

  int eb = (N_EDGES + 255) / 256;
  k_hist<<<eb, 256, 0, stream>>>(eg, deg);
  k_scan<<<1, 256, 0, stream>>>(deg, offs, cursor);
  k_bucket<<<eb, 256, 0, stream>>>(eg, cursor, srcs);
  k_agg<<<(N_NODES + 3) / 4, 256, 0, stream>>>(offs, deg, srcs, m, agg);

  k_gru<<<g1, 256, 0, stream>>>(agg, xr, Wih, Whh, bih, bhh, out);
}

// Round 3
// 228.136 us; speedup vs baseline: 5.2692x; 1.0843x over previous
//
#include <hip/hip_runtime.h>
#include <hip/hip_bf16.h>

#define N_NODES 20000
#define N_EDGES 320000
#define PW 40   // LDS tile pitch in ushorts (80B = 20 banks -> conflict-free frag reads)

typedef __attribute__((ext_vector_type(8))) short short8;
typedef __attribute__((ext_vector_type(4))) float f32x4;

static __device__ __forceinline__ ushort f2bf(float f) {
  union { float f; uint u; } v; v.f = f;
  uint u = v.u;
  uint r = (u + 0x7FFFu + ((u >> 16) & 1u)) >> 16;
  return (ushort)r;
}
static __device__ __forceinline__ float bf2f(ushort s) {
  union { uint u; float f; } v; v.u = ((uint)s) << 16; return v.f;
}

// Stage a 64x32 tile into LDS bf16 [64][PW]. 256 threads: 4/row, 8 elems each.
static __device__ __forceinline__ void stage_f32(ushort* lds, const float* __restrict__ src,
                                                 int ld, int mrem) {
  int t = threadIdx.x;
  int row = t >> 2;
  int col = (t & 3) << 3;
  union { ushort s[8]; uint4 v; } tmp;
  if (row < mrem) {
    const float* p = src + (size_t)row * ld + col;
    float4 v0 = *(const float4*)p;
    float4 v1 = *(const float4*)(p + 4);
    tmp.s[0]=f2bf(v0.x); tmp.s[1]=f2bf(v0.y); tmp.s[2]=f2bf(v0.z); tmp.s[3]=f2bf(v0.w);
    tmp.s[4]=f2bf(v1.x); tmp.s[5]=f2bf(v1.y); tmp.s[6]=f2bf(v1.z); tmp.s[7]=f2bf(v1.w);
  } else {
    tmp.v = make_uint4(0,0,0,0);
  }
  *(uint4*)&lds[row*PW + col] = tmp.v;
}

static __device__ __forceinline__ void stage_bf16(ushort* lds, const ushort* __restrict__ src,
                                                  int ld, int mrem) {
  int t = threadIdx.x;
  int row = t >> 2;
  int col = (t & 3) << 3;
  uint4 v = make_uint4(0,0,0,0);
  if (row < mrem) v = *(const uint4*)(src + (size_t)row * ld + col);
  *(uint4*)&lds[row*PW + col] = v;
}

// ---------------- K0: one-time prep: weights->bf16 (+WcT), deg=0 ----------------
__global__ __launch_bounds__(256) void k_prep(
    const float* __restrict__ Wfc, const float* __restrict__ Wc,
    const float* __restrict__ Wih, const float* __restrict__ Whh,
    ushort* __restrict__ WfcB, ushort* __restrict__ WcTB,
    ushort* __restrict__ WihB, ushort* __restrict__ WhhB, int* __restrict__ deg) {
  int i = blockIdx.x * 256 + threadIdx.x;
  if (i < 131072) WfcB[i] = f2bf(Wfc[i]);
  if (i < 65536) { int j = i >> 8, k = i & 255; WcTB[i] = f2bf(Wc[k * 256 + j]); }
  if (i < 196608) { WihB[i] = f2bf(Wih[i]); WhhB[i] = f2bf(Whh[i]); }
  if (i < N_NODES) deg[i] = 0;
}

// ---------------- K1: xr = relu([x|h] @ Wfc^T + bfc), store bf16 ----------------
__global__ __launch_bounds__(256) void k_fc(
    const float* __restrict__ x, const float* __restrict__ h,
    const ushort* __restrict__ WfcB, const float* __restrict__ bfc,
    ushort* __restrict__ xr) {
  __shared__ ushort sA[64*PW], sB[64*PW];
  int row0 = blockIdx.x * 64;
  int col0 = blockIdx.y * 64;
  int mrem = N_NODES - row0; if (mrem > 64) mrem = 64;
  int w = threadIdx.x >> 6, l = threadIdx.x & 63;
  int wr = (w >> 1) * 32, wc = (w & 1) * 32;
  f32x4 acc[2][2] = {};
  for (int kb = 0; kb < 16; ++kb) {
    int k0 = kb * 32;
    const float* asrc = (k0 < 256) ? (x + (size_t)row0*256 + k0)
                                   : (h + (size_t)row0*256 + (k0-256));
    stage_f32(sA, asrc, 256, mrem);
    stage_bf16(sB, WfcB + (size_t)col0*512 + k0, 512, 64);
    __syncthreads();
    short8 a[2], b[2];
    #pragma unroll
    for (int i=0;i<2;i++) a[i] = *(short8*)&sA[(wr + i*16 + (l&15))*PW + (l>>4)*8];
    #pragma unroll
    for (int i=0;i<2;i++) b[i] = *(short8*)&sB[(wc + i*16 + (l&15))*PW + (l>>4)*8];
    #pragma unroll
    for (int mi=0;mi<2;mi++)
      #pragma unroll
      for (int ni=0;ni<2;ni++)
        acc[mi][ni] = __builtin_amdgcn_mfma_f32_16x16x32_bf16(a[mi], b[ni], acc[mi][ni], 0,0,0);
    __syncthreads();
  }
  #pragma unroll
  for (int mi=0;mi<2;mi++)
    #pragma unroll
    for (int ni=0;ni<2;ni++)
      #pragma unroll
      for (int q=0;q<4;q++) {
        int r = row0 + wr + mi*16 + (l>>4)*4 + q;
        int c = col0 + wc + ni*16 + (l&15);
        if (r < N_NODES) {
          float v = acc[mi][ni][q] + bfc[c];
          v = v > 0.f ? v : 0.f;
          xr[(size_t)r*256 + c] = f2bf(v);
        }
      }
}

// ---------------- K2: m = xr @ WcT^T (NT), bf16 in/out ----------------
__global__ __launch_bounds__(256) void k_conv(
    const ushort* __restrict__ xr, const ushort* __restrict__ WcT,
    ushort* __restrict__ m) {
  __shared__ ushort sA[64*PW], sB[64*PW];
  int row0 = blockIdx.x * 64;
  int col0 = blockIdx.y * 64;
  int mrem = N_NODES - row0; if (mrem > 64) mrem = 64;
  int w = threadIdx.x >> 6, l = threadIdx.x & 63;
  int wr = (w >> 1) * 32, wc = (w & 1) * 32;
  f32x4 acc[2][2] = {};
  for (int kb = 0; kb < 8; ++kb) {
    int k0 = kb * 32;
    stage_bf16(sA, xr + (size_t)row0*256 + k0, 256, mrem);
    stage_bf16(sB, WcT + (size_t)col0*256 + k0, 256, 64);
    __syncthreads();
    short8 a[2], b[2];
    #pragma unroll
    for (int i=0;i<2;i++) a[i] = *(short8*)&sA[(wr + i*16 + (l&15))*PW + (l>>4)*8];
    #pragma unroll
    for (int i=0;i<2;i++) b[i] = *(short8*)&sB[(wc + i*16 + (l&15))*PW + (l>>4)*8];
    #pragma unroll
    for (int mi=0;mi<2;mi++)
      #pragma unroll
      for (int ni=0;ni<2;ni++)
        acc[mi][ni] = __builtin_amdgcn_mfma_f32_16x16x32_bf16(a[mi], b[ni], acc[mi][ni], 0,0,0);
    __syncthreads();
  }
  #pragma unroll
  for (int mi=0;mi<2;mi++)
    #pragma unroll
    for (int ni=0;ni<2;ni++)
      #pragma unroll
      for (int q=0;q<4;q++) {
        int r = row0 + wr + mi*16 + (l>>4)*4 + q;
        int c = col0 + wc + ni*16 + (l&15);
        if (r < N_NODES) m[(size_t)r*256 + c] = f2bf(acc[mi][ni][q]);
      }
}

// ---------------- CSR build: histogram / scan / bucket ----------------
__global__ __launch_bounds__(256) void k_hist(const int* __restrict__ eg, int* __restrict__ deg) {
  int e = blockIdx.x * 256 + threadIdx.x;
  if (e < N_EDGES) atomicAdd(&deg[eg[N_EDGES + e]], 1);
}

__global__ __launch_bounds__(256) void k_scan(const int* __restrict__ deg,
                                              int* __restrict__ offs, int* __restrict__ cursor) {
  __shared__ int part[256];
  int t = threadIdx.x;
  const int CH = 79;  // 256*79 = 20224 >= 20000
  int base = t * CH;
  int s = 0;
  for (int i = 0; i < CH; i++) { int idx = base + i; if (idx < N_NODES) s += deg[idx]; }
  part[t] = s; __syncthreads();
  for (int d = 1; d < 256; d <<= 1) {
    int v = (t >= d) ? part[t - d] : 0;
    __syncthreads();
    part[t] += v;
    __syncthreads();
  }
  int run = (t == 0) ? 0 : part[t - 1];
  for (int i = 0; i < CH; i++) {
    int idx = base + i;
    if (idx < N_NODES) { offs[idx] = run; cursor[idx] = run; run += deg[idx]; }
  }
}

__global__ __launch_bounds__(256) void k_bucket(const int* __restrict__ eg,
                                                int* __restrict__ cursor, int* __restrict__ srcs) {
  int e = blockIdx.x * 256 + threadIdx.x;
  if (e < N_EDGES) {
    int d = eg[N_EDGES + e];
    int slot = atomicAdd(&cursor[d], 1);
    srcs[slot] = eg[e];
  }
}

// ---------------- K3: gather-reduce agg[n] = sum_{src in bucket(n)} m[src] ----------------
__global__ __launch_bounds__(256) void k_agg(
    const int* __restrict__ offs, const int* __restrict__ deg, const int* __restrict__ srcs,
    const ushort* __restrict__ m, ushort* __restrict__ agg) {
  int node = blockIdx.x * 8 + (threadIdx.x >> 5);
  if (node >= N_NODES) return;
  int lane = threadIdx.x & 31;   // 16B per lane: full 512B row per 32-lane group
  int off = offs[node];
  int n = deg[node];
  float a[8] = {};
  int i = 0;
  for (; i + 2 <= n; i += 2) {
    int s0 = srcs[off + i];
    int s1 = srcs[off + i + 1];
    uint4 v0 = *(const uint4*)(m + (size_t)s0 * 256 + lane * 8);
    uint4 v1 = *(const uint4*)(m + (size_t)s1 * 256 + lane * 8);
    const ushort* p0 = (const ushort*)&v0;
    const ushort* p1 = (const ushort*)&v1;
    #pragma unroll
    for (int j = 0; j < 8; j++) a[j] += bf2f(p0[j]) + bf2f(p1[j]);
  }
  if (i < n) {
    int s0 = srcs[off + i];
    uint4 v0 = *(const uint4*)(m + (size_t)s0 * 256 + lane * 8);
    const ushort* p0 = (const ushort*)&v0;
    #pragma unroll
    for (int j = 0; j < 8; j++) a[j] += bf2f(p0[j]);
  }
  union { ushort s[8]; uint4 v; } o;
  #pragma unroll
  for (int j = 0; j < 8; j++) o.s[j] = f2bf(a[j]);
  *(uint4*)(agg + (size_t)node * 256 + lane * 8) = o.v;
}

// ---------------- K4: fused GRU (6 GEMM tiles + elementwise) ----------------
__global__ __launch_bounds__(256) void k_gru(
    const ushort* __restrict__ agg, const ushort* __restrict__ xr,
    const ushort* __restrict__ WihB, const ushort* __restrict__ WhhB,
    const float* __restrict__ bih, const float* __restrict__ bhh,
    float* __restrict__ out) {
  __shared__ ushort sAa[64*PW], sAx[64*PW], sBi[3][64*PW], sBh[3][64*PW];
  int row0 = blockIdx.x * 64;
  int col0 = blockIdx.y * 64;
  int mrem = N_NODES - row0; if (mrem > 64) mrem = 64;
  int w = threadIdx.x >> 6, l = threadIdx.x & 63;
  int wr = (w >> 1) * 32, wc = (w & 1) * 32;
  f32x4 acc[6][2][2] = {};  // 0..2: i_r,i_z,i_n   3..5: h_r,h_z,h_n
  for (int kb = 0; kb < 8; ++kb) {
    int k0 = kb * 32;
    stage_bf16(sAa, agg + (size_t)row0*256 + k0, 256, mrem);
    stage_bf16(sAx, xr  + (size_t)row0*256 + k0, 256, mrem);
    #pragma unroll
    for (int c=0;c<3;c++) {
      stage_bf16(sBi[c], WihB + ((size_t)(c*256 + col0))*256 + k0, 256, 64);
      stage_bf16(sBh[c], WhhB + ((size_t)(c*256 + col0))*256 + k0, 256, 64);
    }
    __syncthreads();
    short8 aa[2], ax[2], b;
    #pragma unroll
    for (int i=0;i<2;i++) {
      aa[i] = *(short8*)&sAa[(wr + i*16 + (l&15))*PW + (l>>4)*8];
      ax[i] = *(short8*)&sAx[(wr + i*16 + (l&15))*PW + (l>>4)*8];
    }
    #pragma unroll
    for (int c=0;c<3;c++) {
      #pragma unroll
      for (int ni=0;ni<2;ni++) {
        b = *(short8*)&sBi[c][(wc + ni*16 + (l&15))*PW + (l>>4)*8];
        #pragma unroll
        for (int mi=0;mi<2;mi++)
          acc[c][mi][ni] = __builtin_amdgcn_mfma_f32_16x16x32_bf16(aa[mi], b, acc[c][mi][ni],0,0,0);
        b = *(short8*)&sBh[c][(wc + ni*16 + (l&15))*PW + (l>>4)*8];
        #pragma unroll
        for (int mi=0;mi<2;mi++)
          acc[3+c][mi][ni] = __builtin_amdgcn_mfma_f32_16x16x32_bf16(ax[mi], b, acc[3+c][mi][ni],0,0,0);
      }
    }
    __syncthreads();
  }
  #pragma unroll
  for (int mi=0;mi<2;mi++)
    #pragma unroll
    for (int ni=0;ni<2;ni++)
      #pragma unroll
      for (int q=0;q<4;q++) {
        int r = row0 + wr + mi*16 + (l>>4)*4 + q;
        int c = col0 + wc + ni*16 + (l&15);
        if (r < N_NODES) {
          float ir  = acc[0][mi][ni][q] + bih[c];
          float iz  = acc[1][mi][ni][q] + bih[256+c];
          float inn = acc[2][mi][ni][q] + bih[512+c];
          float hr  = acc[3][mi][ni][q] + bhh[c];
          float hz  = acc[4][mi][ni][q] + bhh[256+c];
          float hn  = acc[5][mi][ni][q] + bhh[512+c];
          float rg = 1.f/(1.f + __expf(-(ir+hr)));
          float zg = 1.f/(1.f + __expf(-(iz+hz)));
          float ng = tanhf(inn + rg*hn);
          float xv = bf2f(xr[(size_t)r*256 + c]);
          out[(size_t)r*256 + c] = (1.f - zg)*ng + zg*xv;
        }
      }
}

extern "C" void kernel_launch(void* const* d_in, const int* in_sizes, int n_in,
                              void* d_out, int out_size, void* d_ws, size_t ws_size,
                              hipStream_t stream) {
  const float* h   = (const float*)d_in[0];
  const float* x   = (const float*)d_in[1];
  const float* Wfc = (const float*)d_in[3];
  const float* bfc = (const float*)d_in[4];
  const float* Wc  = (const float*)d_in[5];
  const float* Wih = (const float*)d_in[6];
  const float* Whh = (const float*)d_in[7];
  const float* bih = (const float*)d_in[8];
  const float* bhh = (const float*)d_in[9];
  const int*   eg  = (const int*)d_in[10];
  float* out = (float*)d_out;

  char* ws = (char*)d_ws;
  ushort* xr   = (ushort*)ws;                    // 10,240,000 B
  ushort* m    = (ushort*)(ws + 10240000);       // 10,240,000 B
  ushort* agg  = (ushort*)(ws + 20480000);       // 10,240,000 B
  ushort* WfcB = (ushort*)(ws + 30720000);       //    262,144 B
  ushort* WcTB = (ushort*)(ws + 30982144);       //    131,072 B
  ushort* WihB = (ushort*)(ws + 31113216);       //    393,216 B
  ushort* WhhB = (ushort*)(ws + 31506432);       //    393,216 B
  int*    deg    = (int*)(ws + 31899648);        //     80,000 B
  int*    offs   = (int*)(ws + 31979648);        //     80,000 B
  int*    cursor = (int*)(ws + 32059648);        //     80,000 B
  int*    srcs   = (int*)(ws + 32139648);        //  1,280,000 B

  k_prep<<<768, 256, 0, stream>>>(Wfc, Wc, Wih, Whh, WfcB, WcTB, WihB, WhhB, deg);

  dim3 g1(313, 4);
  k_fc<<<g1, 256, 0, stream>>>(x, h, WfcB, bfc, xr);
  k_conv<<<g1, 256, 0, stream>>>(xr, WcTB, m);

  int eb = (N_EDGES + 255) / 256;
  k_hist<<<eb, 256, 0, stream>>>(eg, deg);
  k_scan<<<1, 256, 0, stream>>>(deg, offs, cursor);
  k_bucket<<<eb, 256, 0, stream>>>(eg, cursor, srcs);
  k_agg<<<(N_NODES + 7) / 8, 256, 0, stream>>>(offs, deg, srcs, m, agg);

  k_gru<<<g1, 256, 0, stream>>>(agg, xr, WihB, WhhB, bih, bhh, out);
}

// Round 4
// 222.982 us; speedup vs baseline: 5.3910x; 1.0231x over previous
//
#include <hip/hip_runtime.h>
#include <hip/hip_bf16.h>

#define N_NODES 20000
#define M_PAD   20096   // 157 * 128

typedef __attribute__((ext_vector_type(8))) short short8;
typedef __attribute__((ext_vector_type(4))) float f32x4;

#define MFMA16(a,b,c) __builtin_amdgcn_mfma_f32_16x16x32_bf16(a,b,c,0,0,0)

static __device__ __forceinline__ ushort f2bf(float f) {
  union { float f; uint u; } v; v.f = f;
  uint u = v.u;
  uint r = (u + 0x7FFFu + ((u >> 16) & 1u)) >> 16;
  return (ushort)r;
}
static __device__ __forceinline__ float bf2f(ushort s) {
  union { uint u; float f; } v; v.u = ((uint)s) << 16; return v.f;
}

typedef __attribute__((address_space(1))) const unsigned int guint;
typedef __attribute__((address_space(3))) unsigned int luint;
// async global->LDS, 16B per lane. LDS dest must be wave-uniform (HW adds lane*16).
static __device__ __forceinline__ void gl2lds16(const void* g, void* l) {
  __builtin_amdgcn_global_load_lds((guint*)g, (luint*)l, 16, 0, 0);
}

static __device__ __forceinline__ void cvt8(const float* __restrict__ s, ushort* __restrict__ d) {
  float4 v0 = *(const float4*)s;
  float4 v1 = *(const float4*)(s + 4);
  union { ushort u[8]; uint4 v; } t;
  t.u[0]=f2bf(v0.x); t.u[1]=f2bf(v0.y); t.u[2]=f2bf(v0.z); t.u[3]=f2bf(v0.w);
  t.u[4]=f2bf(v1.x); t.u[5]=f2bf(v1.y); t.u[6]=f2bf(v1.z); t.u[7]=f2bf(v1.w);
  *(uint4*)d = t.v;
}

// ---------------- K0: prep — all weights & inputs -> bf16, deg = 0 ----------------
__global__ __launch_bounds__(256) void k_prep(
    const float* __restrict__ x, const float* __restrict__ h,
    const float* __restrict__ Wfc, const float* __restrict__ Wc,
    const float* __restrict__ Wih, const float* __restrict__ Whh,
    ushort* __restrict__ xB, ushort* __restrict__ hB,
    ushort* __restrict__ WfcB, ushort* __restrict__ WcTB,
    ushort* __restrict__ WihB, ushort* __restrict__ WhhB,
    int* __restrict__ deg) {
  int i = blockIdx.x * 256 + threadIdx.x;
  if (i < 640000) {            // x,h: 20000*256/8
    int off = i * 8;
    cvt8(x + off, xB + off);
    cvt8(h + off, hB + off);
  }
  if (i < 16384) { int off = i * 8; cvt8(Wfc + off, WfcB + off); }          // 131072
  if (i < 24576) { int off = i * 8; cvt8(Wih + off, WihB + off);            // 196608
                   cvt8(Whh + off, WhhB + off); }
  if (i < 65536) { int c = i >> 8, k = i & 255; WcTB[c*256 + k] = f2bf(Wc[k*256 + c]); }
  if (i < N_NODES) deg[i] = 0;
}

// ---------------- generic 128x128 GEMM, dual-A (K-concat at 256), NT ----------------
// C[r][c] = sum_k A(r,k) * B[c][k];  A(r,k) = k<256 ? Alo[r*256+k] : Ahi[r*256+k-256]
template<int EPI>   // 0: plain bf16 store; 1: +bias, relu
__global__ __launch_bounds__(256) void k_gemm(
    const ushort* __restrict__ Alo, const ushort* __restrict__ Ahi,
    const ushort* __restrict__ B, int ldb, int ksteps,
    ushort* __restrict__ C, const float* __restrict__ bias) {
  __shared__ __attribute__((aligned(16))) ushort sA[128*32];
  __shared__ __attribute__((aligned(16))) ushort sB[128*32];
  int row0 = blockIdx.x * 128, col0 = blockIdx.y * 128;
  int t = threadIdx.x;
  int w = t >> 6, l = t & 63;
  int wr = (w >> 1) * 64, wc = (w & 1) * 64;
  // staging geometry: 512 16B-chunks per tile; thread t handles chunks t and t+256
  int ra0 = t >> 2,         ca0 = (t & 3) * 8;
  int ra1 = (t + 256) >> 2, ca1 = (t & 3) * 8;
  ushort* dA0 = sA + (w * 64) * 8;          // wave-uniform dests
  ushort* dA1 = sA + (256 + w * 64) * 8;
  ushort* dB0 = sB + (w * 64) * 8;
  ushort* dB1 = sB + (256 + w * 64) * 8;
  f32x4 acc[4][4] = {};
  for (int ks = 0; ks < ksteps; ++ks) {
    int k0 = ks * 32;
    const ushort* Ab = (k0 < 256) ? Alo : Ahi;
    int ka = k0 & 255;
    gl2lds16(Ab + (size_t)(row0 + ra0) * 256 + ka + ca0, dA0);
    gl2lds16(Ab + (size_t)(row0 + ra1) * 256 + ka + ca1, dA1);
    gl2lds16(B + (size_t)(col0 + ra0) * ldb + k0 + ca0, dB0);
    gl2lds16(B + (size_t)(col0 + ra1) * ldb + k0 + ca1, dB1);
    __syncthreads();
    short8 af[4], bf[4];
    #pragma unroll
    for (int i = 0; i < 4; i++) af[i] = *(short8*)&sA[(wr + i*16 + (l&15))*32 + (l>>4)*8];
    #pragma unroll
    for (int i = 0; i < 4; i++) bf[i] = *(short8*)&sB[(wc + i*16 + (l&15))*32 + (l>>4)*8];
    #pragma unroll
    for (int mi = 0; mi < 4; mi++)
      #pragma unroll
      for (int ni = 0; ni < 4; ni++)
        acc[mi][ni] = MFMA16(af[mi], bf[ni], acc[mi][ni]);
    __syncthreads();
  }
  #pragma unroll
  for (int mi = 0; mi < 4; mi++)
    #pragma unroll
    for (int ni = 0; ni < 4; ni++)
      #pragma unroll
      for (int q = 0; q < 4; q++) {
        int r = row0 + wr + mi*16 + (l>>4)*4 + q;
        int c = col0 + wc + ni*16 + (l&15);
        if (r < N_NODES) {
          float v = acc[mi][ni][q];
          if (EPI == 1) { v += bias[c]; v = v > 0.f ? v : 0.f; }
          C[(size_t)r * 256 + c] = f2bf(v);
        }
      }
}

// ---------------- CSR build ----------------
__global__ __launch_bounds__(256) void k_hist(const int* __restrict__ eg, int* __restrict__ deg) {
  int e = blockIdx.x * 256 + threadIdx.x;
  if (e < 320000) atomicAdd(&deg[eg[320000 + e]], 1);
}

__global__ __launch_bounds__(256) void k_scan(const int* __restrict__ deg,
                                              int* __restrict__ offs, int* __restrict__ cursor) {
  __shared__ int part[256];
  int t = threadIdx.x;
  const int CH = 79;
  int base = t * CH;
  int s = 0;
  for (int i = 0; i < CH; i++) { int idx = base + i; if (idx < N_NODES) s += deg[idx]; }
  part[t] = s; __syncthreads();
  for (int d = 1; d < 256; d <<= 1) {
    int v = (t >= d) ? part[t - d] : 0;
    __syncthreads();
    part[t] += v;
    __syncthreads();
  }
  int run = (t == 0) ? 0 : part[t - 1];
  for (int i = 0; i < CH; i++) {
    int idx = base + i;
    if (idx < N_NODES) { offs[idx] = run; cursor[idx] = run; run += deg[idx]; }
  }
}

__global__ __launch_bounds__(256) void k_bucket(const int* __restrict__ eg,
                                                int* __restrict__ cursor, int* __restrict__ srcs) {
  int e = blockIdx.x * 256 + threadIdx.x;
  if (e < 320000) {
    int d = eg[320000 + e];
    int slot = atomicAdd(&cursor[d], 1);
    srcs[slot] = eg[e];
  }
}

// ---------------- gather-reduce agg[n] = sum m[src] ----------------
__global__ __launch_bounds__(256) void k_agg(
    const int* __restrict__ offs, const int* __restrict__ deg, const int* __restrict__ srcs,
    const ushort* __restrict__ m, ushort* __restrict__ agg) {
  int node = blockIdx.x * 8 + (threadIdx.x >> 5);
  if (node >= N_NODES) return;
  int lane = threadIdx.x & 31;
  int off = offs[node];
  int n = deg[node];
  float a[8] = {};
  int i = 0;
  for (; i + 4 <= n; i += 4) {
    uint4 v0 = *(const uint4*)(m + (size_t)srcs[off+i  ] * 256 + lane * 8);
    uint4 v1 = *(const uint4*)(m + (size_t)srcs[off+i+1] * 256 + lane * 8);
    uint4 v2 = *(const uint4*)(m + (size_t)srcs[off+i+2] * 256 + lane * 8);
    uint4 v3 = *(const uint4*)(m + (size_t)srcs[off+i+3] * 256 + lane * 8);
    const ushort* p0 = (const ushort*)&v0; const ushort* p1 = (const ushort*)&v1;
    const ushort* p2 = (const ushort*)&v2; const ushort* p3 = (const ushort*)&v3;
    #pragma unroll
    for (int j = 0; j < 8; j++) a[j] += (bf2f(p0[j]) + bf2f(p1[j])) + (bf2f(p2[j]) + bf2f(p3[j]));
  }
  for (; i < n; ++i) {
    uint4 v0 = *(const uint4*)(m + (size_t)srcs[off+i] * 256 + lane * 8);
    const ushort* p0 = (const ushort*)&v0;
    #pragma unroll
    for (int j = 0; j < 8; j++) a[j] += bf2f(p0[j]);
  }
  union { ushort s[8]; uint4 v; } o;
  #pragma unroll
  for (int j = 0; j < 8; j++) o.s[j] = f2bf(a[j]);
  *(uint4*)(agg + (size_t)node * 256 + lane * 8) = o.v;
}

// ---------------- fused GRU: 128 rows x 128 cols x {r,z,n} planes ----------------
static __device__ __forceinline__ void gru_phase(
    const ushort* __restrict__ A, const ushort* __restrict__ W,
    int row0, int col0, int t, int w, int l, int wr, int wc,
    ushort* sA, ushort* sBr, ushort* sBz, ushort* sBn,
    f32x4 (&accR)[4][2], f32x4 (&accZ)[4][2], f32x4 (&accN)[4][2]) {
  int r = t >> 2, c8 = (t & 3) * 8;          // 512 threads -> 512 chunks (one tile each)
  ushort* dA = sA  + (w * 64) * 8;
  ushort* dR = sBr + (w * 64) * 8;
  ushort* dZ = sBz + (w * 64) * 8;
  ushort* dN = sBn + (w * 64) * 8;
  for (int kb = 0; kb < 8; ++kb) {
    int k0 = kb * 32;
    gl2lds16(A + (size_t)(row0 + r) * 256 + k0 + c8, dA);
    gl2lds16(W + (size_t)(      col0 + r) * 256 + k0 + c8, dR);
    gl2lds16(W + (size_t)(256 + col0 + r) * 256 + k0 + c8, dZ);
    gl2lds16(W + (size_t)(512 + col0 + r) * 256 + k0 + c8, dN);
    __syncthreads();
    short8 af[4], br[2], bz[2], bn[2];
    #pragma unroll
    for (int i = 0; i < 4; i++) af[i] = *(short8*)&sA[(wr + i*16 + (l&15))*32 + (l>>4)*8];
    #pragma unroll
    for (int i = 0; i < 2; i++) {
      br[i] = *(short8*)&sBr[(wc + i*16 + (l&15))*32 + (l>>4)*8];
      bz[i] = *(short8*)&sBz[(wc + i*16 + (l&15))*32 + (l>>4)*8];
      bn[i] = *(short8*)&sBn[(wc + i*16 + (l&15))*32 + (l>>4)*8];
    }
    #pragma unroll
    for (int mi = 0; mi < 4; mi++)
      #pragma unroll
      for (int ni = 0; ni < 2; ni++) {
        accR[mi][ni] = MFMA16(af[mi], br[ni], accR[mi][ni]);
        accZ[mi][ni] = MFMA16(af[mi], bz[ni], accZ[mi][ni]);
        accN[mi][ni] = MFMA16(af[mi], bn[ni], accN[mi][ni]);
      }
    __syncthreads();
  }
}

__global__ __launch_bounds__(512, 2) void k_gru_fused(
    const ushort* __restrict__ agg, const ushort* __restrict__ xr,
    const ushort* __restrict__ WihB, const ushort* __restrict__ WhhB,
    const float* __restrict__ bih, const float* __restrict__ bhh,
    float* __restrict__ out) {
  __shared__ __attribute__((aligned(16))) ushort smem[4 * 128 * 32];
  ushort* sA  = smem;
  ushort* sBr = smem + 4096;
  ushort* sBz = smem + 8192;
  ushort* sBn = smem + 12288;
  int row0 = blockIdx.x * 128, col0 = blockIdx.y * 128;
  int t = threadIdx.x;
  int w = t >> 6, l = t & 63;
  int wr = (w >> 2) * 64, wc = (w & 3) * 32;
  f32x4 accR[4][2] = {}, accZ[4][2] = {}, accI[4][2] = {}, accH[4][2] = {};
  // phase 1: K 0..255  -> A=agg, W=Wih   (accI = i_n)
  gru_phase(agg, WihB, row0, col0, t, w, l, wr, wc, sA, sBr, sBz, sBn, accR, accZ, accI);
  // phase 2: K 256..511 -> A=xr, W=Whh  (accH = h_n); r,z keep accumulating
  gru_phase(xr, WhhB, row0, col0, t, w, l, wr, wc, sA, sBr, sBz, sBn, accR, accZ, accH);
  #pragma unroll
  for (int mi = 0; mi < 4; mi++)
    #pragma unroll
    for (int ni = 0; ni < 2; ni++)
      #pragma unroll
      for (int q = 0; q < 4; q++) {
        int r = row0 + wr + mi*16 + (l>>4)*4 + q;
        int c = col0 + wc + ni*16 + (l&15);
        if (r < N_NODES) {
          float rg = 1.f / (1.f + __expf(-(accR[mi][ni][q] + bih[c] + bhh[c])));
          float zg = 1.f / (1.f + __expf(-(accZ[mi][ni][q] + bih[256+c] + bhh[256+c])));
          float ng = tanhf((accI[mi][ni][q] + bih[512+c]) + rg * (accH[mi][ni][q] + bhh[512+c]));
          float xv = bf2f(xr[(size_t)r * 256 + c]);
          out[(size_t)r * 256 + c] = (1.f - zg) * ng + zg * xv;
        }
      }
}

extern "C" void kernel_launch(void* const* d_in, const int* in_sizes, int n_in,
                              void* d_out, int out_size, void* d_ws, size_t ws_size,
                              hipStream_t stream) {
  const float* h   = (const float*)d_in[0];
  const float* x   = (const float*)d_in[1];
  const float* Wfc = (const float*)d_in[3];
  const float* bfc = (const float*)d_in[4];
  const float* Wc  = (const float*)d_in[5];
  const float* Wih = (const float*)d_in[6];
  const float* Whh = (const float*)d_in[7];
  const float* bih = (const float*)d_in[8];
  const float* bhh = (const float*)d_in[9];
  const int*   eg  = (const int*)d_in[10];
  float* out = (float*)d_out;

  char* ws = (char*)d_ws;
  // M_PAD*256*2 = 10,289,152 per [M][256] bf16 buffer
  ushort* xr   = (ushort*)(ws);                  // live to the end
  ushort* xB   = (ushort*)(ws + 10289152);       // fc input; dead after fc
  ushort* m    = (ushort*)(ws + 10289152);       // conv out — ALIASES xB (safe: fc done)
  ushort* hB   = (ushort*)(ws + 20578304);       // fc input; dead after fc
  ushort* agg  = (ushort*)(ws + 20578304);       // ALIASES hB (safe: written after fc)
  ushort* WfcB = (ushort*)(ws + 30867456);       //   262,144
  ushort* WihB = (ushort*)(ws + 31129600);       //   393,216
  ushort* WhhB = (ushort*)(ws + 31522816);       //   393,216
  ushort* WcTB = (ushort*)(ws + 31916032);       //   131,072
  int*    deg    = (int*)(ws + 32047104);        //    80,000
  int*    offs   = (int*)(ws + 32127104);        //    80,000
  int*    cursor = (int*)(ws + 32207104);        //    80,000
  int*    srcs   = (int*)(ws + 32287104);        // 1,280,000  -> total 33,567,104

  k_prep<<<2560, 256, 0, stream>>>(x, h, Wfc, Wc, Wih, Whh,
                                   xB, hB, WfcB, WcTB, WihB, WhhB, deg);

  dim3 gg(157, 2);
  k_gemm<1><<<gg, 256, 0, stream>>>(xB, hB, WfcB, 512, 16, xr, bfc);
  k_gemm<0><<<gg, 256, 0, stream>>>(xr, xr, WcTB, 256, 8, m, nullptr);

  int eb = (320000 + 255) / 256;
  k_hist<<<eb, 256, 0, stream>>>(eg, deg);
  k_scan<<<1, 256, 0, stream>>>(deg, offs, cursor);
  k_bucket<<<eb, 256, 0, stream>>>(eg, cursor, srcs);
  k_agg<<<(N_NODES + 7) / 8, 256, 0, stream>>>(offs, deg, srcs, m, agg);

  k_gru_fused<<<gg, 512, 0, stream>>>(agg, xr, WihB, WhhB, bih, bhh, out);
}